// Round 8
// baseline (898.797 us; speedup 1.0000x reference)
//
#include <hip/hip_runtime.h>
#include <math.h>

#define N_ 32
#define C_ 512
#define CR_ 64
#define HW_ 3136
#define HW4_ 784
#define QROWS_ 4096     // rows per quarter = 8 samples * 512 channels
constexpr float EPS = 1e-5f;

typedef float f4 __attribute__((ext_vector_type(4)));

// ---------- device: pool one (n,c) row (256 threads) ----------
__device__ __forceinline__ void pool_row(const float* __restrict__ x,
                                         float* __restrict__ pooled, int row) {
    const f4* xr = reinterpret_cast<const f4*>(x + (size_t)row * HW_);
    float acc = 0.f;
    for (int j = threadIdx.x; j < HW4_; j += 256) {
        f4 v = xr[j];
        acc += (v.x + v.y) + (v.z + v.w);
    }
    for (int o = 32; o; o >>= 1) acc += __shfl_down(acc, o, 64);
    __shared__ float s[4];
    if ((threadIdx.x & 63) == 0) s[threadIdx.x >> 6] = acc;
    __syncthreads();
    if (threadIdx.x == 0)
        pooled[row] = (s[0] + s[1] + s[2] + s[3]) * (1.0f / HW_);
}

// ---------- device: scale one row; gate recomputed redundantly ----------
__device__ __forceinline__ void scale_row(const float* __restrict__ x,
    const float* __restrict__ pooled,
    const float* __restrict__ w1, const float* __restrict__ b1,
    const float* __restrict__ gw1, const float* __restrict__ gb1,
    const float* __restrict__ w2, const float* __restrict__ b2,
    const float* __restrict__ gw2, const float* __restrict__ gb2,
    float* __restrict__ out, int row)
{
    const int tid = threadIdx.x;
    const int n = row >> 9, c = row & (C_ - 1);
    const f4* xr = reinterpret_cast<const f4*>(x + (size_t)row * HW_);
    f4* orow = reinterpret_cast<f4*>(out + (size_t)row * HW_);

    // issue the row loads early; they complete under the gate compute
    f4 v0 = xr[tid], v1 = xr[tid + 256], v2 = xr[tid + 512], v3;
    const bool has4 = tid < (HW4_ - 768);
    if (has4) v3 = xr[tid + 768];

    __shared__ float sp[C_];
    __shared__ float sh[CR_];
    __shared__ float sred[4];
    __shared__ float sgate;
    const int base = n * C_;
    sp[tid]       = pooled[base + tid];
    sp[tid + 256] = pooled[base + 256 + tid];
    __syncthreads();

    // h[r] = dot(sp, w1[r,:]) + b1[r]; 4 threads per r
    {
        const int r = tid >> 2, l4 = tid & 3;
        float a = 0.f;
        for (int cc = l4; cc < C_; cc += 4) a += sp[cc] * w1[r * C_ + cc];
        a += __shfl_xor(a, 1, 64);
        a += __shfl_xor(a, 2, 64);
        if (l4 == 0) sh[r] = a + b1[r];
    }
    __syncthreads();

    // GroupNorm(1) over 64 + ELU (first wave)
    if (tid < 64) {
        const float v = sh[tid];
        float s = v;
        for (int o = 32; o; o >>= 1) s += __shfl_xor(s, o, 64);
        const float mu = s * (1.0f / CR_);
        const float d = v - mu;
        float vv = d * d;
        for (int o = 32; o; o >>= 1) vv += __shfl_xor(vv, o, 64);
        float xn = d * rsqrtf(vv * (1.0f / CR_) + EPS) * gw1[tid] + gb1[tid];
        sh[tid] = xn > 0.f ? xn : expm1f(xn);   // ELU alpha=1
    }
    __syncthreads();

    // g for channels tid and tid+256 (needed for GN2 statistics)
    float g0 = b2[tid], g1 = b2[tid + 256];
    #pragma unroll 8
    for (int r = 0; r < CR_; ++r) {
        g0 += sh[r] * w2[tid * CR_ + r];
        g1 += sh[r] * w2[(tid + 256) * CR_ + r];
    }
    float s = g0 + g1;
    for (int o = 32; o; o >>= 1) s += __shfl_xor(s, o, 64);
    if ((tid & 63) == 0) sred[tid >> 6] = s;
    __syncthreads();
    const float mu = (sred[0] + sred[1] + sred[2] + sred[3]) * (1.0f / C_);
    const float d0 = g0 - mu, d1 = g1 - mu;
    float vv = d0 * d0 + d1 * d1;
    for (int o = 32; o; o >>= 1) vv += __shfl_xor(vv, o, 64);
    __syncthreads();
    if ((tid & 63) == 0) sred[tid >> 6] = vv;
    __syncthreads();
    const float rstd = rsqrtf((sred[0] + sred[1] + sred[2] + sred[3]) * (1.0f / C_) + EPS);

    // only this row's channel c is needed
    if (tid == (c & 255)) {
        const float d = (c & 256) ? d1 : d0;
        const float xn = d * rstd * gw2[c] + gb2[c];
        sgate = 1.f / (1.f + expf(-xn));
    }
    __syncthreads();
    const float g = sgate;

    v0 *= g; v1 *= g; v2 *= g;
    __builtin_nontemporal_store(v0, &orow[tid]);
    __builtin_nontemporal_store(v1, &orow[tid + 256]);
    __builtin_nontemporal_store(v2, &orow[tid + 512]);
    if (has4) { v3 *= g; __builtin_nontemporal_store(v3, &orow[tid + 768]); }
}

// ---------- globals ----------
__global__ __launch_bounds__(256) void pool_kernel(const float* __restrict__ x,
                                                   float* __restrict__ pooled,
                                                   int rowBase) {
    pool_row(x, pooled, rowBase + blockIdx.x);
}

__global__ __launch_bounds__(256) void scale_kernel(const float* __restrict__ x,
    const float* __restrict__ pooled,
    const float* __restrict__ w1, const float* __restrict__ b1,
    const float* __restrict__ gw1, const float* __restrict__ gb1,
    const float* __restrict__ w2, const float* __restrict__ b2,
    const float* __restrict__ gw2, const float* __restrict__ gb2,
    float* __restrict__ out, int rowBase) {
    scale_row(x, pooled, w1, b1, gw1, gb1, w2, b2, gw2, gb2, out,
              rowBase + blockIdx.x);
}

// even blocks: scale quarter i-1 (L3-hot reads); odd blocks: pool quarter i
__global__ __launch_bounds__(256) void combo_kernel(const float* __restrict__ x,
    float* __restrict__ pooled,
    const float* __restrict__ w1, const float* __restrict__ b1,
    const float* __restrict__ gw1, const float* __restrict__ gb1,
    const float* __restrict__ w2, const float* __restrict__ b2,
    const float* __restrict__ gw2, const float* __restrict__ gb2,
    float* __restrict__ out, int scaleBase, int poolBase) {
    const int bid = blockIdx.x;
    if (bid & 1) {
        pool_row(x, pooled, poolBase + (bid >> 1));
    } else {
        scale_row(x, pooled, w1, b1, gw1, gb1, w2, b2, gw2, gb2, out,
                  scaleBase + (bid >> 1));
    }
}

extern "C" void kernel_launch(void* const* d_in, const int* in_sizes, int n_in,
                              void* d_out, int out_size, void* d_ws, size_t ws_size,
                              hipStream_t stream) {
    const float* x   = (const float*)d_in[0];
    const float* w1  = (const float*)d_in[1];
    const float* b1  = (const float*)d_in[2];
    const float* gw1 = (const float*)d_in[3];
    const float* gb1 = (const float*)d_in[4];
    const float* w2  = (const float*)d_in[5];
    const float* b2  = (const float*)d_in[6];
    const float* gw2 = (const float*)d_in[7];
    const float* gb2 = (const float*)d_in[8];
    float* out = (float*)d_out;

    float* pooled = (float*)d_ws;   // N_*C_ floats

    pool_kernel<<<QROWS_, 256, 0, stream>>>(x, pooled, 0);
    combo_kernel<<<2 * QROWS_, 256, 0, stream>>>(x, pooled, w1, b1, gw1, gb1,
                                                 w2, b2, gw2, gb2, out,
                                                 0, QROWS_);
    combo_kernel<<<2 * QROWS_, 256, 0, stream>>>(x, pooled, w1, b1, gw1, gb1,
                                                 w2, b2, gw2, gb2, out,
                                                 QROWS_, 2 * QROWS_);
    combo_kernel<<<2 * QROWS_, 256, 0, stream>>>(x, pooled, w1, b1, gw1, gb1,
                                                 w2, b2, gw2, gb2, out,
                                                 2 * QROWS_, 3 * QROWS_);
    scale_kernel<<<QROWS_, 256, 0, stream>>>(x, pooled, w1, b1, gw1, gb1,
                                             w2, b2, gw2, gb2, out, 3 * QROWS_);
}

// Round 9
// 250.610 us; speedup vs baseline: 3.5864x; 3.5864x over previous
//
#include <hip/hip_runtime.h>
#include <math.h>

#define N_ 32
#define C_ 512
#define CR_ 64
#define HW_ 3136
#define HW4_ 784
#define SPC_ 4                    // samples per chunk
#define NCH_ 8                    // chunks
#define CHROWS_ (SPC_ * C_)       // 2048 rows per chunk
constexpr float EPS = 1e-5f;

typedef float f4 __attribute__((ext_vector_type(4)));

// ---------- pool one (n,c) row (256 threads) ----------
__device__ __forceinline__ void pool_row(const float* __restrict__ x,
                                         float* __restrict__ pooled, int row) {
    const f4* xr = reinterpret_cast<const f4*>(x + (size_t)row * HW_);
    float acc = 0.f;
    for (int j = threadIdx.x; j < HW4_; j += 256) {
        f4 v = xr[j];
        acc += (v.x + v.y) + (v.z + v.w);
    }
    for (int o = 32; o; o >>= 1) acc += __shfl_down(acc, o, 64);
    __shared__ float s[4];
    if ((threadIdx.x & 63) == 0) s[threadIdx.x >> 6] = acc;
    __syncthreads();
    if (threadIdx.x == 0)
        pooled[row] = (s[0] + s[1] + s[2] + s[3]) * (1.0f / HW_);
}

// ---------- scale one row with precomputed gate (256 threads) ----------
__device__ __forceinline__ void scale_row(const float* __restrict__ x,
                                          const float* __restrict__ gate,
                                          float* __restrict__ out, int row) {
    const float g = gate[row];
    const f4* xr = reinterpret_cast<const f4*>(x + (size_t)row * HW_);
    f4* orow = reinterpret_cast<f4*>(out + (size_t)row * HW_);
    for (int j = threadIdx.x; j < HW4_; j += 256) {
        f4 v = xr[j];
        v *= g;
        __builtin_nontemporal_store(v, &orow[j]);
    }
}

// ---------- full gate for one sample (256 threads) ----------
__device__ __forceinline__ void gate_sample(
    const float* __restrict__ pooled,
    const float* __restrict__ w1, const float* __restrict__ b1,
    const float* __restrict__ gw1, const float* __restrict__ gb1,
    const float* __restrict__ w2, const float* __restrict__ b2,
    const float* __restrict__ gw2, const float* __restrict__ gb2,
    float* __restrict__ gate, int n)
{
    const int tid = threadIdx.x;
    __shared__ float sp[C_];
    __shared__ float sh[CR_];
    __shared__ float sred[4];
    const int base = n * C_;
    sp[tid]       = pooled[base + tid];
    sp[tid + 256] = pooled[base + 256 + tid];
    __syncthreads();

    // h[r] = dot(sp, w1[r,:]) + b1[r]; 4 threads per r
    {
        const int r = tid >> 2, l4 = tid & 3;
        float a = 0.f;
        for (int cc = l4; cc < C_; cc += 4) a += sp[cc] * w1[r * C_ + cc];
        a += __shfl_xor(a, 1, 64);
        a += __shfl_xor(a, 2, 64);
        if (l4 == 0) sh[r] = a + b1[r];
    }
    __syncthreads();

    // GroupNorm(1) over 64 + ELU (first wave)
    if (tid < 64) {
        const float v = sh[tid];
        float s = v;
        for (int o = 32; o; o >>= 1) s += __shfl_xor(s, o, 64);
        const float mu = s * (1.0f / CR_);
        const float d = v - mu;
        float vv = d * d;
        for (int o = 32; o; o >>= 1) vv += __shfl_xor(vv, o, 64);
        float xn = d * rsqrtf(vv * (1.0f / CR_) + EPS) * gw1[tid] + gb1[tid];
        sh[tid] = xn > 0.f ? xn : expm1f(xn);   // ELU alpha=1
    }
    __syncthreads();

    // g for channels tid and tid+256
    float g0 = b2[tid], g1 = b2[tid + 256];
    #pragma unroll 8
    for (int r = 0; r < CR_; ++r) {
        g0 += sh[r] * w2[tid * CR_ + r];
        g1 += sh[r] * w2[(tid + 256) * CR_ + r];
    }
    // GroupNorm(1) over 512
    float s = g0 + g1;
    for (int o = 32; o; o >>= 1) s += __shfl_xor(s, o, 64);
    if ((tid & 63) == 0) sred[tid >> 6] = s;
    __syncthreads();
    const float mu = (sred[0] + sred[1] + sred[2] + sred[3]) * (1.0f / C_);
    const float d0 = g0 - mu, d1 = g1 - mu;
    float vv = d0 * d0 + d1 * d1;
    for (int o = 32; o; o >>= 1) vv += __shfl_xor(vv, o, 64);
    __syncthreads();
    if ((tid & 63) == 0) sred[tid >> 6] = vv;
    __syncthreads();
    const float rstd = rsqrtf((sred[0] + sred[1] + sred[2] + sred[3]) * (1.0f / C_) + EPS);
    const float xn0 = d0 * rstd * gw2[tid] + gb2[tid];
    const float xn1 = d1 * rstd * gw2[tid + 256] + gb2[tid + 256];
    gate[base + tid]       = 1.f / (1.f + expf(-xn0));
    gate[base + tid + 256] = 1.f / (1.f + expf(-xn1));
}

// ---------- mega kernel: role by blockIdx ----------
// blocks [0, nScale+nPool): scale/pool (interleaved even/odd when both present)
// blocks [nScale+nPool, +nGate): gate samples
__global__ __launch_bounds__(256) void mega_kernel(
    const float* __restrict__ x,
    float* __restrict__ pooled, float* __restrict__ gate,
    const float* __restrict__ w1, const float* __restrict__ b1,
    const float* __restrict__ gw1, const float* __restrict__ gb1,
    const float* __restrict__ w2, const float* __restrict__ b2,
    const float* __restrict__ gw2, const float* __restrict__ gb2,
    float* __restrict__ out,
    int scaleBase, int nScale, int poolBase, int nPool,
    int gateSampleBase)
{
    const int bid = blockIdx.x;
    const int nSP = nScale + nPool;
    if (bid < nSP) {
        if (nScale > 0 && nPool > 0) {
            if (bid & 1) pool_row(x, pooled, poolBase + (bid >> 1));
            else         scale_row(x, gate, out, scaleBase + (bid >> 1));
        } else if (nPool > 0) {
            pool_row(x, pooled, poolBase + bid);
        } else {
            scale_row(x, gate, out, scaleBase + bid);
        }
    } else {
        gate_sample(pooled, w1, b1, gw1, gb1, w2, b2, gw2, gb2,
                    gate, gateSampleBase + (bid - nSP));
    }
}

extern "C" void kernel_launch(void* const* d_in, const int* in_sizes, int n_in,
                              void* d_out, int out_size, void* d_ws, size_t ws_size,
                              hipStream_t stream) {
    const float* x   = (const float*)d_in[0];
    const float* w1  = (const float*)d_in[1];
    const float* b1  = (const float*)d_in[2];
    const float* gw1 = (const float*)d_in[3];
    const float* gb1 = (const float*)d_in[4];
    const float* w2  = (const float*)d_in[5];
    const float* b2  = (const float*)d_in[6];
    const float* gw2 = (const float*)d_in[7];
    const float* gb2 = (const float*)d_in[8];
    float* out = (float*)d_out;

    float* pooled = (float*)d_ws;            // N_*C_ floats
    float* gate   = pooled + N_ * C_;        // N_*C_ floats

    #define LAUNCH(grid, sB, nS, pB, nP, gS) \
        mega_kernel<<<(grid), 256, 0, stream>>>(x, pooled, gate, w1, b1, gw1, gb1, \
                                                w2, b2, gw2, gb2, out, (sB), (nS), (pB), (nP), (gS))

    // K0: pool c0
    LAUNCH(CHROWS_, 0, 0, 0, CHROWS_, 0);
    // K1: pool c1 + gate chunk0 samples
    LAUNCH(CHROWS_ + SPC_, 0, 0, CHROWS_, CHROWS_, 0);
    // K2..K7: scale c_{i-2} + pool c_i + gate chunk_{i-1}
    for (int i = 2; i < NCH_; ++i) {
        LAUNCH(2 * CHROWS_ + SPC_,
               (i - 2) * CHROWS_, CHROWS_,
               i * CHROWS_, CHROWS_,
               (i - 1) * SPC_);
    }
    // K8: scale c6 + gate chunk7
    LAUNCH(CHROWS_ + SPC_, (NCH_ - 2) * CHROWS_, CHROWS_, 0, 0, (NCH_ - 1) * SPC_);
    // K9: scale c7
    LAUNCH(CHROWS_, (NCH_ - 1) * CHROWS_, CHROWS_, 0, 0, 0);
    #undef LAUNCH
}

// Round 10
// 128.709 us; speedup vs baseline: 6.9832x; 1.9471x over previous
//
#include <hip/hip_runtime.h>
#include <math.h>

#define N_ 32
#define C_ 512
#define CR_ 64
#define HW_ 3136
#define HW4_ 784
#define HROWS_ 8192     // rows per half = 16 samples * 512 channels
constexpr float EPS = 1e-5f;

typedef float f4 __attribute__((ext_vector_type(4)));

// ---------- pool one (n,c) row (256 threads) ----------
__device__ __forceinline__ void pool_row(const float* __restrict__ x,
                                         float* __restrict__ pooled, int row) {
    const f4* xr = reinterpret_cast<const f4*>(x + (size_t)row * HW_);
    float acc = 0.f;
    for (int j = threadIdx.x; j < HW4_; j += 256) {
        f4 v = xr[j];
        acc += (v.x + v.y) + (v.z + v.w);
    }
    for (int o = 32; o; o >>= 1) acc += __shfl_down(acc, o, 64);
    __shared__ float s[4];
    if ((threadIdx.x & 63) == 0) s[threadIdx.x >> 6] = acc;
    __syncthreads();
    if (threadIdx.x == 0)
        pooled[row] = (s[0] + s[1] + s[2] + s[3]) * (1.0f / HW_);
}

// ---------- scale one row with precomputed gate (256 threads) ----------
__device__ __forceinline__ void scale_row(const float* __restrict__ x,
                                          const float* __restrict__ gate,
                                          float* __restrict__ out, int row) {
    const float g = gate[row];
    const f4* xr = reinterpret_cast<const f4*>(x + (size_t)row * HW_);
    f4* orow = reinterpret_cast<f4*>(out + (size_t)row * HW_);
    for (int j = threadIdx.x; j < HW4_; j += 256) {
        f4 v = xr[j];
        v *= g;
        __builtin_nontemporal_store(v, &orow[j]);
    }
}

// ---------- full gate for one sample (256 threads) ----------
__device__ __forceinline__ void gate_sample(
    const float* __restrict__ pooled,
    const float* __restrict__ w1, const float* __restrict__ b1,
    const float* __restrict__ gw1, const float* __restrict__ gb1,
    const float* __restrict__ w2, const float* __restrict__ b2,
    const float* __restrict__ gw2, const float* __restrict__ gb2,
    float* __restrict__ gate, int n)
{
    const int tid = threadIdx.x;
    __shared__ float sp[C_];
    __shared__ float sh[CR_];
    __shared__ float sred[4];
    const int base = n * C_;
    sp[tid]       = pooled[base + tid];
    sp[tid + 256] = pooled[base + 256 + tid];
    __syncthreads();

    // h[r] = dot(sp, w1[r,:]) + b1[r]; 4 threads per r
    {
        const int r = tid >> 2, l4 = tid & 3;
        float a = 0.f;
        for (int cc = l4; cc < C_; cc += 4) a += sp[cc] * w1[r * C_ + cc];
        a += __shfl_xor(a, 1, 64);
        a += __shfl_xor(a, 2, 64);
        if (l4 == 0) sh[r] = a + b1[r];
    }
    __syncthreads();

    // GroupNorm(1) over 64 + ELU (first wave)
    if (tid < 64) {
        const float v = sh[tid];
        float s = v;
        for (int o = 32; o; o >>= 1) s += __shfl_xor(s, o, 64);
        const float mu = s * (1.0f / CR_);
        const float d = v - mu;
        float vv = d * d;
        for (int o = 32; o; o >>= 1) vv += __shfl_xor(vv, o, 64);
        float xn = d * rsqrtf(vv * (1.0f / CR_) + EPS) * gw1[tid] + gb1[tid];
        sh[tid] = xn > 0.f ? xn : expm1f(xn);   // ELU alpha=1
    }
    __syncthreads();

    // g for channels tid and tid+256
    float g0 = b2[tid], g1 = b2[tid + 256];
    #pragma unroll 8
    for (int r = 0; r < CR_; ++r) {
        g0 += sh[r] * w2[tid * CR_ + r];
        g1 += sh[r] * w2[(tid + 256) * CR_ + r];
    }
    // GroupNorm(1) over 512
    float s = g0 + g1;
    for (int o = 32; o; o >>= 1) s += __shfl_xor(s, o, 64);
    if ((tid & 63) == 0) sred[tid >> 6] = s;
    __syncthreads();
    const float mu = (sred[0] + sred[1] + sred[2] + sred[3]) * (1.0f / C_);
    const float d0 = g0 - mu, d1 = g1 - mu;
    float vv = d0 * d0 + d1 * d1;
    for (int o = 32; o; o >>= 1) vv += __shfl_xor(vv, o, 64);
    __syncthreads();
    if ((tid & 63) == 0) sred[tid >> 6] = vv;
    __syncthreads();
    const float rstd = rsqrtf((sred[0] + sred[1] + sred[2] + sred[3]) * (1.0f / C_) + EPS);
    const float xn0 = d0 * rstd * gw2[tid] + gb2[tid];
    const float xn1 = d1 * rstd * gw2[tid + 256] + gb2[tid + 256];
    gate[base + tid]       = 1.f / (1.f + expf(-xn0));
    gate[base + tid + 256] = 1.f / (1.f + expf(-xn1));
}

// ---------- step kernel ----------
// blocks [0, nGate): gate samples gateBase..  (FIRST -> scheduled early, hidden)
// blocks [nGate, nGate+nMain): pool (mode=0) or scale (mode=1) rows rowBase..
__global__ __launch_bounds__(256) void step_kernel(
    const float* __restrict__ x,
    float* __restrict__ pooled, float* __restrict__ gate,
    const float* __restrict__ w1, const float* __restrict__ b1,
    const float* __restrict__ gw1, const float* __restrict__ gb1,
    const float* __restrict__ w2, const float* __restrict__ b2,
    const float* __restrict__ gw2, const float* __restrict__ gb2,
    float* __restrict__ out,
    int nGate, int gateBase, int mode, int rowBase)
{
    const int bid = blockIdx.x;
    if (bid < nGate) {
        gate_sample(pooled, w1, b1, gw1, gb1, w2, b2, gw2, gb2,
                    gate, gateBase + bid);
    } else {
        const int row = rowBase + (bid - nGate);
        if (mode == 0) pool_row(x, pooled, row);
        else           scale_row(x, gate, out, row);
    }
}

extern "C" void kernel_launch(void* const* d_in, const int* in_sizes, int n_in,
                              void* d_out, int out_size, void* d_ws, size_t ws_size,
                              hipStream_t stream) {
    const float* x   = (const float*)d_in[0];
    const float* w1  = (const float*)d_in[1];
    const float* b1  = (const float*)d_in[2];
    const float* gw1 = (const float*)d_in[3];
    const float* gb1 = (const float*)d_in[4];
    const float* w2  = (const float*)d_in[5];
    const float* b2  = (const float*)d_in[6];
    const float* gw2 = (const float*)d_in[7];
    const float* gb2 = (const float*)d_in[8];
    float* out = (float*)d_out;

    float* pooled = (float*)d_ws;            // N_*C_ floats
    float* gate   = pooled + N_ * C_;        // N_*C_ floats

    #define LAUNCH(grid, nG, gB, md, rB) \
        step_kernel<<<(grid), 256, 0, stream>>>(x, pooled, gate, w1, b1, gw1, gb1, \
                                                w2, b2, gw2, gb2, out, (nG), (gB), (md), (rB))

    // K0: pool h0
    LAUNCH(HROWS_, 0, 0, 0, 0);
    // K1: gate(h0 samples 0..15) || pool h1
    LAUNCH(16 + HROWS_, 16, 0, 0, HROWS_);
    // K2: gate(h1 samples 16..31) || scale h0 (x_h0 L3-resident)
    LAUNCH(16 + HROWS_, 16, 16, 1, 0);
    // K3: scale h1
    LAUNCH(HROWS_, 0, 0, 1, HROWS_);
    #undef LAUNCH
}